// Round 12
// baseline (94.670 us; speedup 1.0000x reference)
//
#include <hip/hip_runtime.h>
#include <hip/hip_bf16.h>

// Problem: B=4096, IN=1024, H=1024.
// pre = x@U^T + h@W^T + Ub -> gates -> h_t, c_t   (fused after convert)
// GEMM: M=4096 (batch), N=4096 (4H permuted), K=2048 (IN+H concat)
//
// Round-12: TWO BARRIER DOMAINS PER CU (m114/m97 implicit-overlap mechanism).
//   BM=128, BN=256, BK=32 -> grid 512 blocks = 2 blocks/CU.
//   8 waves/block (2M x 4N), wave tile 64x64, acc[4][4] (64 regs).
//   3-slot LDS ring (24 KB/slot, 72 KB/block; 144 KB/CU for 2 blocks).
//   3 loads/thread/tile; counted vmcnt(3); ONE barrier per K-tile.
//   __launch_bounds__(512,4) -> <=128 regs so 16 waves/CU fit.
//   Ring ledger: body t stages tile t+2 into slot (t+2)%3 (!= slot t%3 being
//   read); WAIT vmcnt(3) at body end leaves t+2's 3 loads in flight and
//   forces t+1's landed; BAR makes them visible to all waves. Write-safety:
//   slot s's readers (body t) consume reads via MFMA-lgkm before BAR(t);
//   s is restaged at body t+1 (after BAR). Prologue: stage t0,t1; vmcnt(3);
//   BAR. Tail bodies stage clamped tsrc=63 (dummy, count-preserving).

#define BATCH 4096
#define HID   1024
#define KDIM  2048

#define BM 128
#define BN 256
#define BK 32
#define NT (KDIM / BK)        // 64 K-tiles
#define SLOT_BYTES 24576u     // A 8 KB + B 16 KB

typedef __bf16 bf16x8 __attribute__((ext_vector_type(8)));
typedef float  f32x4  __attribute__((ext_vector_type(4)));

__device__ __forceinline__ void async_load16(const void* g, void* l) {
    __builtin_amdgcn_global_load_lds(
        (const __attribute__((address_space(1))) void*)g,
        (__attribute__((address_space(3))) void*)l,
        16, 0, 0);
}

__device__ __forceinline__ float sigmoidf_(float v) {
    return 1.0f / (1.0f + __expf(-v));
}
__device__ __forceinline__ float tanhf_(float v) {
    return 1.0f - 2.0f / (__expf(2.0f * v) + 1.0f);
}

// ---------------------------------------------------------------------------
// Kernel 1: f32 -> bf16 conversion + K-concat; B side gate-permuted.
// (unchanged from r7-r11; permutation p = bn*256 + wn*64 + g*16 + c)
// ---------------------------------------------------------------------------
__global__ __launch_bounds__(256) void convert_kernel(
    const float* __restrict__ x, const float* __restrict__ h,
    const float* __restrict__ U, const float* __restrict__ W,
    __hip_bfloat16* __restrict__ Acat, __hip_bfloat16* __restrict__ Bcat)
{
    const int CH_PER_MAT = (4096 * KDIM) / 8;
    int idx = blockIdx.x * blockDim.x + threadIdx.x;
    bool isB = idx >= CH_PER_MAT;
    int c = isB ? (idx - CH_PER_MAT) : idx;
    int row  = c >> 8;
    int col  = (c & 255) << 3;
    int srow = row;
    if (isB) {
        int g  = (row >> 4) & 3;
        int j  = ((row >> 8) << 6) + (((row >> 6) & 3) << 4) + (row & 15);
        srow = g * 1024 + j;
    }
    const float* src;
    if (col < 1024) src = (isB ? U : x) + (size_t)srow * 1024 + col;
    else            src = (isB ? W : h) + (size_t)srow * 1024 + (col - 1024);
    float4 v0 = *(const float4*)(src);
    float4 v1 = *(const float4*)(src + 4);
    __hip_bfloat16 tmp[8];
    tmp[0] = __float2bfloat16(v0.x); tmp[1] = __float2bfloat16(v0.y);
    tmp[2] = __float2bfloat16(v0.z); tmp[3] = __float2bfloat16(v0.w);
    tmp[4] = __float2bfloat16(v1.x); tmp[5] = __float2bfloat16(v1.y);
    tmp[6] = __float2bfloat16(v1.z); tmp[7] = __float2bfloat16(v1.w);
    __hip_bfloat16* dst = (isB ? Bcat : Acat) + (size_t)row * KDIM + col;
    *(bf16x8*)dst = *(const bf16x8*)tmp;
}

// ---------------------------------------------------------------------------
// Kernel 2: fused bf16 GEMM + LSTM gates, 2-blocks/CU ring schedule.
// ---------------------------------------------------------------------------
__global__ __launch_bounds__(512, 4) void gemm_lstm_kernel(
    const __hip_bfloat16* __restrict__ A,   // [4096][2048]
    const __hip_bfloat16* __restrict__ Bm,  // [4096][2048] gate-permuted
    const float* __restrict__ Ub,           // [4096]
    const float* __restrict__ c_prev,       // [4096][1024]
    float* __restrict__ out)                // h_t ++ c_t
{
    __shared__ __align__(16) unsigned char smem[3 * SLOT_BYTES];  // 72 KB

    const int tid  = threadIdx.x;
    const int lane = tid & 63;
    const int wid  = tid >> 6;
    const int wm   = wid >> 2;     // 0..1  (M half of 128)
    const int wn   = wid & 3;      // 0..3  (N quarter of 256)

    // L2 map: 512 blocks; each XCD owns an 8bm x 8bn rectangle of the
    // 32 x 16 block grid. Bijective: 32 = 4*8, 16 = 2*8.
    int wg  = blockIdx.x;
    const int xcd = wg & 7;
    const int i_  = wg >> 3;                 // 0..63
    const int bm = ((xcd >> 1) << 3) + (i_ >> 3);   // 0..31
    const int bn = ((xcd & 1) << 3) + (i_ & 7);     // 0..15

    const __hip_bfloat16* Ab = A  + (size_t)bm * BM * KDIM;
    const __hip_bfloat16* Bb = Bm + (size_t)bn * BN * KDIM;

    // --- ds_read addressing: rows of 32 bf16 = 64 B = 4 x 16B slots.
    // swizzle: phys_slot = kq ^ x(row), x(r) = (r ^ (r>>2)) & 3.
    // For fragment rows r = 16*m + frow, x(r) = (frow ^ (frow>>2)) & 3
    // (frag bases are multiples of 16) -> per-lane constant.
    const int frow = lane & 15;
    const int kq   = lane >> 4;                         // 0..3
    const int xw   = (frow ^ (frow >> 2)) & 3;
    const unsigned sp = (unsigned)((kq ^ xw) << 4);     // byte slot in row
    const unsigned arow = (unsigned)(wm * 64 + frow);   // + m*16
    const unsigned brow = (unsigned)(wn * 64 + frow);   // + n*16

    // --- staging: A 512 chunks (1/thread), B 1024 chunks (2/thread).
    // linear LDS dest (chunk ch -> byte ch*16); source slot pre-swizzled:
    // g = (ch&3) ^ x(ch>>2). For B chunk 512+tid, row = 128 + (tid>>2) and
    // x(128+q) = x(q), so the same per-thread offset serves all three.
    const int rA  = tid >> 2;
    const int gA8 = (((tid & 3) ^ ((rA ^ (rA >> 2)) & 3)) << 3);
    const size_t ga = (size_t)rA * KDIM + gA8;          // elem offset

    f32x4 acc[4][4] = {};

#define RD16(B) (*(const bf16x8*)(smem + (B)))
#define STAGE(TSRC, SLOT) do { \
    unsigned char* _b = smem + (SLOT) * SLOT_BYTES; \
    const size_t _k = (size_t)(TSRC) * BK; \
    async_load16(Ab + ga + _k, _b + (unsigned)tid * 16u); \
    async_load16(Bb + ga + _k, _b + 8192u + (unsigned)tid * 16u); \
    async_load16(Bb + ga + (size_t)128 * KDIM + _k, \
                 _b + 16384u + (unsigned)tid * 16u); } while (0)

    // ---- prologue: stage t0 -> slot0, t1 -> slot1; vmcnt(3) lands t0 ----
    STAGE(0, 0);
    STAGE(1, 1);
    asm volatile("s_waitcnt vmcnt(3)" ::: "memory");
    __builtin_amdgcn_s_barrier();

    int s_cur = 0, s_dst = 2;
#pragma unroll 1
    for (int t = 0; t < NT; ++t) {
        const int tsrc = (t + 2 < NT) ? (t + 2) : (NT - 1);  // clamp (dummy tail)
        STAGE(tsrc, s_dst);

        const unsigned ab = (unsigned)s_cur * SLOT_BYTES;
        const unsigned bb = ab + 8192u;
        bf16x8 af[4], bf[4];
#pragma unroll
        for (int m = 0; m < 4; ++m)
            af[m] = RD16(ab + (arow + m * 16u) * 64u + sp);
#pragma unroll
        for (int n = 0; n < 4; ++n)
            bf[n] = RD16(bb + (brow + n * 16u) * 64u + sp);

#pragma unroll
        for (int m = 0; m < 4; ++m)
#pragma unroll
            for (int n = 0; n < 4; ++n)
                acc[m][n] = __builtin_amdgcn_mfma_f32_16x16x32_bf16(
                    af[m], bf[n], acc[m][n], 0, 0, 0);

        // t+1 landed (t+2's 3 loads stay in flight); visible to all after BAR
        asm volatile("s_waitcnt vmcnt(3)" ::: "memory");
        __builtin_amdgcn_s_barrier();

        s_cur = (s_cur == 2) ? 0 : s_cur + 1;
        s_dst = (s_dst == 2) ? 0 : s_dst + 1;
    }
#undef RD16
#undef STAGE

    // ---- fused epilogue: gates lane-local thanks to B permutation ----
    // permuted col p = bn*256 + wn*64 + g*16 + c  ->  gate g, j = bn*64+wn*16+c
    const int j = bn * 64 + wn * 16 + frow;
    const float bf_ = Ub[j];
    const float bi_ = Ub[1024 + j];
    const float bo_ = Ub[2048 + j];
    const float bg_ = Ub[3072 + j];
    const int row0 = bm * BM + wm * 64 + ((lane >> 4) << 2);

    float cp[4][4];
#pragma unroll
    for (int m = 0; m < 4; ++m)
#pragma unroll
        for (int r = 0; r < 4; ++r)
            cp[m][r] = c_prev[(size_t)(row0 + m * 16 + r) * HID + j];

#pragma unroll
    for (int m = 0; m < 4; ++m) {
#pragma unroll
        for (int r = 0; r < 4; ++r) {
            const int row = row0 + m * 16 + r;
            const float f  = sigmoidf_(acc[m][0][r] + bf_);
            const float it = sigmoidf_(acc[m][1][r] + bi_);
            const float o  = sigmoidf_(acc[m][2][r] + bo_);
            const float gg = tanhf_(acc[m][3][r] + bg_);
            const float cv = f * cp[m][r] + it * gg;
            const float hv = o * tanhf_(cv);
            out[(size_t)row * HID + j] = hv;
            out[(size_t)BATCH * HID + (size_t)row * HID + j] = cv;
        }
    }
}

// ---------------------------------------------------------------------------
extern "C" void kernel_launch(void* const* d_in, const int* in_sizes, int n_in,
                              void* d_out, int out_size, void* d_ws, size_t ws_size,
                              hipStream_t stream) {
    const float* x      = (const float*)d_in[0];
    const float* h_prev = (const float*)d_in[1];
    const float* c_prev = (const float*)d_in[2];
    const float* U_w    = (const float*)d_in[3];
    const float* U_b    = (const float*)d_in[4];
    const float* W_w    = (const float*)d_in[5];
    float* out = (float*)d_out;

    char* ws = (char*)d_ws;
    __hip_bfloat16* Acat = (__hip_bfloat16*)ws;                      // 16 MB
    __hip_bfloat16* Bcat = (__hip_bfloat16*)(ws + (16u << 20));      // 16 MB

    convert_kernel<<<8192, 256, 0, stream>>>(x, h_prev, U_w, W_w, Acat, Bcat);
    // (4096/128) * (4096/256) = 32 * 16 = 512 blocks, 2 per CU
    gemm_lstm_kernel<<<512, 512, 0, stream>>>(Acat, Bcat, U_b, c_prev, out);
}